// Round 5
// baseline (7282.480 us; speedup 1.0000x reference)
//
#include <hip/hip_runtime.h>
#include <hip/hip_fp16.h>
#include <hip/hip_cooperative_groups.h>

namespace cg = cooperative_groups;

typedef _Float16 half8 __attribute__((ext_vector_type(8)));
typedef float floatx4 __attribute__((ext_vector_type(4)));

#define NB 128
#define NT 256
#define NIN 128
#define NH 1024

// ws layout (bytes):
//  h rings: 8-deep (L2-inv only every 8th phase)
//  PART: pairwise K-partial exchange buffers [2 kg][128 cg][2 layers][32 n][64 b] fp32
#define H0_OFF   0u          // 8 x 128*1024 half = 2097152 B
#define H1_OFF   2097152u    // 2097152 B
#define PART_OFF 4194304u    // 2*128*4096 floats = 4194304 B
#define BAR_OFF  8388608u    // 16 group lines @256B, root @4096, flag @4352, pairflags @8192

// LDS layout (bytes):
//  w0l: 32 n x (640+10) half = 41600            [x(128) | Whh0 K-half(512)]
//  w1l: 32 n x (1024+10) half= 66176  @41600    [Wih1 K-half | Whh1 K-half]
//  gs0: 32 n x 132 float     = 16896  @107776   col-major gate tile (all 128 b)
//  gs1: 32 n x 132 float     = 16896  @124672
//  prl: 4096 float           = 16384  @141568   staged partner partial
//  bs0/bs1: 32+32 float      = 256    @157952   -> total 158208 (<160K, 1 WG/CU)
// strides: words % 32 == 5 (coprime) -> weight ds_read_b128 rows hit disjoint
// banks. KEPT from R4 (bank conflicts 2.68e8 -> 5.87e7). The R4 rotj/rotk
// stagger is REVERTED: lockstep same-address reads are TCC-merged (broadcast),
// de-correlating them doubled runtime (3876 -> 7282 us).
#define W0STRIDE 650
#define W1STRIDE 1034
#define GSTRIDE  132
#define LDS_BYTES 158208

__device__ __forceinline__ float sigm(float x) { return 1.0f / (1.0f + __expf(-x)); }
__device__ __forceinline__ float tanh_fast(float x) { return 1.0f - 2.0f / (__expf(2.0f * x) + 1.0f); }

// agent-scope relaxed stores: write-through past non-coherent XCD L2 to LLC.
// After __syncthreads' vmcnt(0) drain these are globally visible.
__device__ __forceinline__ void st2_agent(_Float16* p, float v) {
    _Float16 hv = (_Float16)v;
    unsigned short u;
    __builtin_memcpy(&u, &hv, 2);
    __hip_atomic_store((unsigned short*)p, u, __ATOMIC_RELAXED, __HIP_MEMORY_SCOPE_AGENT);
}
__device__ __forceinline__ void st4_agent(float* p, float v) {
    __hip_atomic_store(p, v, __ATOMIC_RELAXED, __HIP_MEMORY_SCOPE_AGENT);
}
__device__ __forceinline__ float ld4_agent(const float* p) {
    return __hip_atomic_load(p, __ATOMIC_RELAXED, __HIP_MEMORY_SCOPE_AGENT);
}

// Two-level grid barrier: 16 groups x 16 WGs. Ring-aware acquire fences:
// full agent fence (L1+XCD-L2 inv) only every 8th epoch (ring reuse boundary),
// cheap L1-only inv otherwise.
__device__ __forceinline__ void gbar_arrive(char* bar, unsigned epoch, int wg) {
    unsigned* gcnt = (unsigned*)(bar + (wg & 15) * 256);
    unsigned old = __hip_atomic_fetch_add(gcnt, 1u, __ATOMIC_RELAXED, __HIP_MEMORY_SCOPE_AGENT);
    if (old == epoch * 16u - 1u) {
        unsigned* rcnt = (unsigned*)(bar + 4096);
        unsigned rold = __hip_atomic_fetch_add(rcnt, 1u, __ATOMIC_RELAXED, __HIP_MEMORY_SCOPE_AGENT);
        if (rold == epoch * 16u - 1u) {
            unsigned* flag = (unsigned*)(bar + 4352);
            __hip_atomic_store(flag, epoch, __ATOMIC_RELAXED, __HIP_MEMORY_SCOPE_AGENT);
        }
    }
}
__device__ __forceinline__ void gbar_wait(char* bar, unsigned epoch) {
    unsigned* flag = (unsigned*)(bar + 4352);
    while (__hip_atomic_load(flag, __ATOMIC_RELAXED, __HIP_MEMORY_SCOPE_AGENT) < epoch)
        __builtin_amdgcn_s_sleep(1);
    if ((epoch & 7u) == 0u) {
        __builtin_amdgcn_fence(__ATOMIC_ACQUIRE, "agent");
    } else {
        asm volatile("s_waitcnt vmcnt(0)\n\tbuffer_inv sc0" ::: "memory");
    }
}

// K-split across WG pairs: WG (g = wg>>7, c = wg&127) owns 8 h-cols
// [c*8, c*8+8) and K-half [g*512, g*512+512). Partials summed via pairwise
// LLC exchange; activation ownership split by batch half.
__global__ void __launch_bounds__(512, 2)
lstm_persist(const float* __restrict__ x,
             const float* __restrict__ Wih0, const float* __restrict__ Whh0,
             const float* __restrict__ bih0, const float* __restrict__ bhh0,
             const float* __restrict__ Wih1, const float* __restrict__ Whh1,
             const float* __restrict__ bih1, const float* __restrict__ bhh1,
             const float* __restrict__ Wd, const float* __restrict__ bd,
             float* __restrict__ out, char* __restrict__ wsc)
{
    cg::grid_group grid = cg::this_grid();
    const int wg   = blockIdx.x;      // 0..255
    const int g    = wg >> 7;         // kgroup: K-half
    const int c    = wg & 127;        // colgroup: h-cols [c*8, c*8+8)
    const int tid  = threadIdx.x;     // 0..511
    const int r    = tid >> 6;        // rowgroup 0..7: batches [r*16, r*16+16)
    const int lane = tid & 63;
    const int l15  = lane & 15;
    const int quad = lane >> 4;

    _Float16* h0b = (_Float16*)(wsc + H0_OFF);   // [8][128][1024] ring
    _Float16* h1b = (_Float16*)(wsc + H1_OFF);   // [8][128][1024] ring
    char* bar = wsc + BAR_OFF;
    float* part = (float*)(wsc + PART_OFF);
    float* my_part = part + (size_t)(g * 128 + c) * 4096;        // my partial for partner's batches
    float* pr_part = part + (size_t)((1 - g) * 128 + c) * 4096;  // partner's partial for my batches
    unsigned* myflag = (unsigned*)(bar + 8192 + c * 128 + g * 4);
    unsigned* prflag = (unsigned*)(bar + 8192 + c * 128 + (1 - g) * 4);

    extern __shared__ char smem[];
    _Float16* w0l = (_Float16*)(smem);            // [32][650]
    _Float16* w1l = (_Float16*)(smem + 41600);    // [32][1034]
    float*    gs0 = (float*)(smem + 107776);      // [32][132] col-major
    float*    gs1 = (float*)(smem + 124672);      // [32][132]
    float*    prl = (float*)(smem + 141568);      // [4096] staged partner partial
    float*    bs0 = (float*)(smem + 157952);      // [32]
    float*    bs1 = (float*)(smem + 158080);      // [32]

    // ---------- init: stage weight slice (8 cols x K-half) into LDS ----------
    for (int i = tid; i < 32 * 640; i += 512) {
        int n = i / 640, k = i - n * 640;
        int gcol = ((n >> 3) << 10) + (c << 3) + (n & 7);
        float v = (k < NIN) ? Wih0[gcol * NIN + k] : Whh0[gcol * NH + g * 512 + (k - NIN)];
        w0l[n * W0STRIDE + k] = (_Float16)v;
    }
    for (int i = tid; i < 32 * 1024; i += 512) {
        int n = i >> 10, k = i & 1023;
        int gcol = ((n >> 3) << 10) + (c << 3) + (n & 7);
        float v = (k < 512) ? Wih1[gcol * NH + g * 512 + k] : Whh1[gcol * NH + g * 512 + (k - 512)];
        w1l[n * W1STRIDE + k] = (_Float16)v;
    }
    if (tid < 32) {
        int n = tid;
        int gcol = ((n >> 3) << 10) + (c << 3) + (n & 7);
        bs0[n] = bih0[gcol] + bhh0[gcol];
        bs1[n] = bih1[gcol] + bhh1[gcol];
    }

    // ---------- init: zero h rings + barrier/pairflag state ----------
    {
        const int gtid = wg * 512 + tid;
        const int gsz  = 256 * 512;
        float* hz = (float*)wsc;     // both h rings = 4 MiB = 1048576 floats
        for (int i = gtid; i < 1048576; i += gsz) hz[i] = 0.0f;
        if (wg == 0) {
            if (tid < 18) {
                if (tid < 16)       *(unsigned*)(bar + tid * 256) = 0u;
                else if (tid == 16) *(unsigned*)(bar + 4096) = 0u;
                else                *(unsigned*)(bar + 4352) = 0u;
            }
            for (int i = tid; i < 4096; i += 512) *(unsigned*)(bar + 8192 + i * 4) = 0u;
        }
    }
    __builtin_amdgcn_fence(__ATOMIC_RELEASE, "agent");
    grid.sync();
    __builtin_amdgcn_fence(__ATOMIC_ACQUIRE, "agent");

    float c0 = 0.0f, c1 = 0.0f;          // cell state: 1 (b,hcol) pair/thread
    const int bh_   = tid >> 3;          // local batch 0..63
    const int cl_   = tid & 7;           // local h-col 0..7
    const int bact  = g * 64 + bh_;      // owned global batch
    const int hcol  = (c << 3) + cl_;

    // B-fragment row bases in LDS (per nt tile), quad*8 baked in
    const _Float16* bw0[2];  const _Float16* bw1i[2];  const _Float16* bw1h[2];  const _Float16* bx[2];
    #pragma unroll
    for (int nt = 0; nt < 2; ++nt) {
        bw0[nt]  = w0l + (nt * 16 + l15) * W0STRIDE + NIN + quad * 8;  // Whh0 K-half
        bw1i[nt] = w1l + (nt * 16 + l15) * W1STRIDE + quad * 8;        // Wih1 K-half
        bw1h[nt] = bw1i[nt] + 512;                                     // Whh1 K-half
        bx[nt]   = w0l + (nt * 16 + l15) * W0STRIDE + quad * 8;        // x weights (full 128)
    }
    const int aoff = (r * 16 + l15) * NH + g * 512 + quad * 8;         // A-row offset in h arrays

    floatx4 accx0 = {0.f,0.f,0.f,0.f}, accx1 = {0.f,0.f,0.f,0.f};

    // x-part of layer0 gates (h-independent, g==0 WGs only), fp32 x converted on the fly
    auto xpart = [&](int t) {
        floatx4 ax0 = {0.f,0.f,0.f,0.f}, ax1 = {0.f,0.f,0.f,0.f};
        const float* xr = x + (size_t)(r * 16 + l15) * (NT * NIN) + t * NIN + quad * 8;
        #pragma unroll
        for (int j = 0; j < 4; ++j) {
            floatx4 f0 = *(const floatx4*)(xr + j * 32);
            floatx4 f1 = *(const floatx4*)(xr + j * 32 + 4);
            half8 a;
            a[0]=(_Float16)f0[0]; a[1]=(_Float16)f0[1]; a[2]=(_Float16)f0[2]; a[3]=(_Float16)f0[3];
            a[4]=(_Float16)f1[0]; a[5]=(_Float16)f1[1]; a[6]=(_Float16)f1[2]; a[7]=(_Float16)f1[3];
            half8 b0 = *(const half8*)(bx[0] + j * 32);
            half8 b1 = *(const half8*)(bx[1] + j * 32);
            ax0 = __builtin_amdgcn_mfma_f32_16x16x32_f16(a, b0, ax0, 0, 0, 0);
            ax1 = __builtin_amdgcn_mfma_f32_16x16x32_f16(a, b1, ax1, 0, 0, 0);
        }
        accx0 = ax0; accx1 = ax1;
    };

    if (g == 0) xpart(0);   // prologue

    // phase p: computes h0[p] (p<NT) and h1[p-1] (p>=1)
    // ring reads: h0[p-1] -> buf (p+7)&7 ; h1[p-2] -> buf (p+6)&7
    for (int p = 0; p <= NT; ++p) {
        const _Float16* arow_h0 = h0b + (size_t)((p + 7) & 7) * (NB * NH) + aoff;
        const _Float16* arow_h1 = h1b + (size_t)((p + 6) & 7) * (NB * NH) + aoff;

        floatx4 acc0[2]  = { accx0, accx1 };
        floatx4 acc1[2]  = { {0.f,0.f,0.f,0.f}, {0.f,0.f,0.f,0.f} };
        floatx4 acc1b[2] = { {0.f,0.f,0.f,0.f}, {0.f,0.f,0.f,0.f} };

        if (p >= 1 && p < NT) {
            #pragma unroll
            for (int jb = 0; jb < 4; ++jb) {
                half8 a0v[4], a1v[4];
                #pragma unroll
                for (int j = 0; j < 4; ++j) a0v[j] = *(const half8*)(arow_h0 + (jb * 4 + j) * 32);
                #pragma unroll
                for (int j = 0; j < 4; ++j) a1v[j] = *(const half8*)(arow_h1 + (jb * 4 + j) * 32);
                #pragma unroll
                for (int j = 0; j < 4; ++j) {
                    #pragma unroll
                    for (int nt = 0; nt < 2; ++nt) {
                        half8 v0 = *(const half8*)(bw0[nt]  + (jb * 4 + j) * 32);
                        half8 v1 = *(const half8*)(bw1i[nt] + (jb * 4 + j) * 32);
                        half8 v2 = *(const half8*)(bw1h[nt] + (jb * 4 + j) * 32);
                        acc0[nt]  = __builtin_amdgcn_mfma_f32_16x16x32_f16(a0v[j], v0, acc0[nt], 0, 0, 0);
                        acc1[nt]  = __builtin_amdgcn_mfma_f32_16x16x32_f16(a0v[j], v1, acc1[nt], 0, 0, 0);
                        acc1b[nt] = __builtin_amdgcn_mfma_f32_16x16x32_f16(a1v[j], v2, acc1b[nt], 0, 0, 0);
                    }
                }
            }
        } else if (p == NT) {  // layer1 only
            #pragma unroll
            for (int jb = 0; jb < 4; ++jb) {
                half8 a0v[4], a1v[4];
                #pragma unroll
                for (int j = 0; j < 4; ++j) a0v[j] = *(const half8*)(arow_h0 + (jb * 4 + j) * 32);
                #pragma unroll
                for (int j = 0; j < 4; ++j) a1v[j] = *(const half8*)(arow_h1 + (jb * 4 + j) * 32);
                #pragma unroll
                for (int j = 0; j < 4; ++j) {
                    #pragma unroll
                    for (int nt = 0; nt < 2; ++nt) {
                        half8 v1 = *(const half8*)(bw1i[nt] + (jb * 4 + j) * 32);
                        half8 v2 = *(const half8*)(bw1h[nt] + (jb * 4 + j) * 32);
                        acc1[nt]  = __builtin_amdgcn_mfma_f32_16x16x32_f16(a0v[j], v1, acc1[nt], 0, 0, 0);
                        acc1b[nt] = __builtin_amdgcn_mfma_f32_16x16x32_f16(a1v[j], v2, acc1b[nt], 0, 0, 0);
                    }
                }
            }
        }
        // p == 0: h rings are zeros; gates = x-part only
        acc1[0] = acc1[0] + acc1b[0];
        acc1[1] = acc1[1] + acc1b[1];

        // stash K-partial gate tiles (all 128 batches) to LDS, col-major
        #pragma unroll
        for (int nt = 0; nt < 2; ++nt) {
            if (p < NT)  *(floatx4*)&gs0[(nt * 16 + l15) * GSTRIDE + r * 16 + quad * 4] = acc0[nt];
            if (p >= 1)  *(floatx4*)&gs1[(nt * 16 + l15) * GSTRIDE + r * 16 + quad * 4] = acc1[nt];
        }
        __syncthreads();

        // ---- pairwise K-partial exchange: send my partial for PARTNER's batches
        // idx = l*2048 + n*64 + bo  (l=layer, n=gatecol, bo=partner-local batch)
        #pragma unroll
        for (int rep = 0; rep < 8; ++rep) {
            int idx = rep * 512 + tid;
            int l = idx >> 11, rem = idx & 2047;
            int n = rem >> 6, bo = (rem & 63) + (1 - g) * 64;
            float v = l ? gs1[n * GSTRIDE + bo] : gs0[n * GSTRIDE + bo];
            st4_agent(my_part + idx, v);
        }
        __syncthreads();                       // drains vmcnt: partial stores at LLC
        if (tid == 0) {
            __hip_atomic_store(myflag, (unsigned)(p + 1), __ATOMIC_RELAXED, __HIP_MEMORY_SCOPE_AGENT);
            while (__hip_atomic_load(prflag, __ATOMIC_RELAXED, __HIP_MEMORY_SCOPE_AGENT) < (unsigned)(p + 1))
                __builtin_amdgcn_s_sleep(1);
        }
        __syncthreads();                       // partner's partial is at LLC now

        // stage partner partial into LDS (dense agent loads bypass stale L1/L2)
        #pragma unroll
        for (int rep = 0; rep < 8; ++rep) {
            int idx = rep * 512 + tid;
            prl[idx] = ld4_agent(pr_part + idx);
        }
        __syncthreads();

        // activation: this WG owns batches [g*64, g*64+64) for its 8 h-cols
        {
            if (p < NT) {
                float gi = gs0[(cl_)      * GSTRIDE + bact] + prl[(cl_)      * 64 + bh_] + bs0[cl_];
                float gf = gs0[(8 + cl_)  * GSTRIDE + bact] + prl[(8 + cl_)  * 64 + bh_] + bs0[8 + cl_];
                float gg = gs0[(16 + cl_) * GSTRIDE + bact] + prl[(16 + cl_) * 64 + bh_] + bs0[16 + cl_];
                float go = gs0[(24 + cl_) * GSTRIDE + bact] + prl[(24 + cl_) * 64 + bh_] + bs0[24 + cl_];
                c0 = sigm(gf) * c0 + sigm(gi) * tanh_fast(gg);
                float h = sigm(go) * tanh_fast(c0);
                st2_agent(h0b + (size_t)(p & 7) * (NB * NH) + bact * NH + hcol, h);   // h0[p]
            }
            if (p >= 1) {
                float gi = gs1[(cl_)      * GSTRIDE + bact] + prl[2048 + (cl_)      * 64 + bh_] + bs1[cl_];
                float gf = gs1[(8 + cl_)  * GSTRIDE + bact] + prl[2048 + (8 + cl_)  * 64 + bh_] + bs1[8 + cl_];
                float gg = gs1[(16 + cl_) * GSTRIDE + bact] + prl[2048 + (16 + cl_) * 64 + bh_] + bs1[16 + cl_];
                float go = gs1[(24 + cl_) * GSTRIDE + bact] + prl[2048 + (24 + cl_) * 64 + bh_] + bs1[24 + cl_];
                c1 = sigm(gf) * c1 + sigm(gi) * tanh_fast(gg);
                float h = sigm(go) * tanh_fast(c1);
                st2_agent(h1b + (size_t)((p + 7) & 7) * (NB * NH) + bact * NH + hcol, h);  // h1[p-1]
            }
        }

        // ---- global barrier with overlap: next x-part hides the spin window
        __syncthreads();                       // drains vmcnt: h-stores at LLC
        if (tid == 0) gbar_arrive(bar, (unsigned)(p + 1), wg);
        if (g == 0 && p + 1 < NT) xpart(p + 1);
        if (tid == 0) gbar_wait(bar, (unsigned)(p + 1));
        __syncthreads();
    }

    // dense head: WG b (<128) computes out[b][0..1] from h1[255] (ring slot 7)
    if (wg < NB) {
        const _Float16* hrow = h1b + (size_t)7 * (NB * NH) + wg * NH;
        float hk0 = (float)hrow[tid * 2];
        float hk1 = (float)hrow[tid * 2 + 1];
        float p0 = hk0 * Wd[tid * 2] + hk1 * Wd[tid * 2 + 1];
        float p1 = hk0 * Wd[NH + tid * 2] + hk1 * Wd[NH + tid * 2 + 1];
        #pragma unroll
        for (int off = 32; off; off >>= 1) {
            p0 += __shfl_down(p0, off);
            p1 += __shfl_down(p1, off);
        }
        float* red = gs0;  // reuse LDS
        if (lane == 0) { red[r * 2] = p0; red[r * 2 + 1] = p1; }
        __syncthreads();
        if (tid < 2) {
            float s = bd[tid];
            #pragma unroll
            for (int w = 0; w < 8; ++w) s += red[w * 2 + tid];
            out[wg * 2 + tid] = tanhf(s);
        }
    }
}

extern "C" void kernel_launch(void* const* d_in, const int* in_sizes, int n_in,
                              void* d_out, int out_size, void* d_ws, size_t ws_size,
                              hipStream_t stream) {
    const float* x    = (const float*)d_in[0];
    const float* Wih0 = (const float*)d_in[1];
    const float* Whh0 = (const float*)d_in[2];
    const float* bih0 = (const float*)d_in[3];
    const float* bhh0 = (const float*)d_in[4];
    const float* Wih1 = (const float*)d_in[5];
    const float* Whh1 = (const float*)d_in[6];
    const float* bih1 = (const float*)d_in[7];
    const float* bhh1 = (const float*)d_in[8];
    const float* Wd   = (const float*)d_in[9];
    const float* bd   = (const float*)d_in[10];
    float* out = (float*)d_out;
    char* ws = (char*)d_ws;

    hipFuncSetAttribute((const void*)lstm_persist,
                        hipFuncAttributeMaxDynamicSharedMemorySize, LDS_BYTES);

    void* kargs[] = { &x, &Wih0, &Whh0, &bih0, &bhh0, &Wih1, &Whh1, &bih1, &bhh1,
                      &Wd, &bd, &out, &ws };
    hipLaunchCooperativeKernel((void*)lstm_persist, dim3(256), dim3(512),
                               kargs, LDS_BYTES, stream);
}

// Round 6
// 3823.360 us; speedup vs baseline: 1.9047x; 1.9047x over previous
//
#include <hip/hip_runtime.h>
#include <hip/hip_fp16.h>
#include <hip/hip_cooperative_groups.h>

namespace cg = cooperative_groups;

typedef _Float16 half8 __attribute__((ext_vector_type(8)));
typedef float floatx4 __attribute__((ext_vector_type(4)));

#define NB 128
#define NT 256
#define NIN 128
#define NH 1024

// ws layout (bytes):
//  h rings: 8-deep (L2-inv only every 8th phase)
//  PART: pairwise K-partial exchange buffers [2 kg][128 cg][2 layers][32 n][64 b] fp32
#define H0_OFF   0u          // 8 x 128*1024 half = 2097152 B
#define H1_OFF   2097152u    // 2097152 B
#define PART_OFF 4194304u    // 2*128*4096 floats = 4194304 B
#define BAR_OFF  8388608u    // 16 group lines @256B, root @4096, flag @4352, pairflags @8192

// LDS layout (bytes):
//  w0l: 32 n x (640+8) half  = 41472            [x(128) | Whh0 K-half(512)]
//  w1l: 32 n x (1024+8) half = 66048  @41472    [Wih1 K-half | Whh1 K-half]
//  gs0: 32 n x 132 float     = 16896  @107520   col-major gate tile (all 128 b)
//  gs1: 32 n x 132 float     = 16896  @124416
//  prl: 2 x 32 x 68 float    = 17408  @141312   staged partner partial (PADDED)
//  bs0/bs1: 32+32 float      = 256    @158720   -> total 158976 (<160K, 1 WG/CU)
//
// STRIDE RULES learned R4/R5 (the 2x regression):
//  - B-row stride MUST be a multiple of 8 halves (16 B) or ds_read_b128 is
//    misaligned and the compiler splits it into b32/b64 pieces (~4x LDS ops,
//    3876 -> 7282 us). 648/1032 halves = 324/516 words (== 4 mod 32) already
//    give the minimal 2-way (free, m136) pattern for the 16-row x quad reads.
//  - prl activation reads had word-stride 64 (== 0 mod 32): 64 lanes -> 8
//    banks = 8-way conflict. Pad to 68 (== 4 mod 32): bank = 4*cl + bh,
//    ~conflict-free. Write side (n fixed/wave, bo = lane) stays clean.
#define W0STRIDE 648
#define W1STRIDE 1032
#define GSTRIDE  132
#define PRLSTRIDE 68
#define PRL_L     2176   // 32*68: float offset between the two layers in prl
#define LDS_BYTES 158976

__device__ __forceinline__ float sigm(float x) { return 1.0f / (1.0f + __expf(-x)); }
__device__ __forceinline__ float tanh_fast(float x) { return 1.0f - 2.0f / (__expf(2.0f * x) + 1.0f); }

// agent-scope relaxed stores: write-through past non-coherent XCD L2 to LLC.
// After __syncthreads' vmcnt(0) drain these are globally visible.
__device__ __forceinline__ void st2_agent(_Float16* p, float v) {
    _Float16 hv = (_Float16)v;
    unsigned short u;
    __builtin_memcpy(&u, &hv, 2);
    __hip_atomic_store((unsigned short*)p, u, __ATOMIC_RELAXED, __HIP_MEMORY_SCOPE_AGENT);
}
__device__ __forceinline__ void st4_agent(float* p, float v) {
    __hip_atomic_store(p, v, __ATOMIC_RELAXED, __HIP_MEMORY_SCOPE_AGENT);
}
__device__ __forceinline__ float ld4_agent(const float* p) {
    return __hip_atomic_load(p, __ATOMIC_RELAXED, __HIP_MEMORY_SCOPE_AGENT);
}

// Two-level grid barrier: 16 groups x 16 WGs. Ring-aware acquire fences:
// full agent fence (L1+XCD-L2 inv) only every 8th epoch (ring reuse boundary),
// cheap L1-only inv otherwise.
__device__ __forceinline__ void gbar_arrive(char* bar, unsigned epoch, int wg) {
    unsigned* gcnt = (unsigned*)(bar + (wg & 15) * 256);
    unsigned old = __hip_atomic_fetch_add(gcnt, 1u, __ATOMIC_RELAXED, __HIP_MEMORY_SCOPE_AGENT);
    if (old == epoch * 16u - 1u) {
        unsigned* rcnt = (unsigned*)(bar + 4096);
        unsigned rold = __hip_atomic_fetch_add(rcnt, 1u, __ATOMIC_RELAXED, __HIP_MEMORY_SCOPE_AGENT);
        if (rold == epoch * 16u - 1u) {
            unsigned* flag = (unsigned*)(bar + 4352);
            __hip_atomic_store(flag, epoch, __ATOMIC_RELAXED, __HIP_MEMORY_SCOPE_AGENT);
        }
    }
}
__device__ __forceinline__ void gbar_wait(char* bar, unsigned epoch) {
    unsigned* flag = (unsigned*)(bar + 4352);
    while (__hip_atomic_load(flag, __ATOMIC_RELAXED, __HIP_MEMORY_SCOPE_AGENT) < epoch)
        __builtin_amdgcn_s_sleep(1);
    if ((epoch & 7u) == 0u) {
        __builtin_amdgcn_fence(__ATOMIC_ACQUIRE, "agent");
    } else {
        asm volatile("s_waitcnt vmcnt(0)\n\tbuffer_inv sc0" ::: "memory");
    }
}

// K-split across WG pairs: WG (g = wg>>7, c = wg&127) owns 8 h-cols
// [c*8, c*8+8) and K-half [g*512, g*512+512). Partials summed via pairwise
// LLC exchange; activation ownership split by batch half.
__global__ void __launch_bounds__(512, 2)
lstm_persist(const float* __restrict__ x,
             const float* __restrict__ Wih0, const float* __restrict__ Whh0,
             const float* __restrict__ bih0, const float* __restrict__ bhh0,
             const float* __restrict__ Wih1, const float* __restrict__ Whh1,
             const float* __restrict__ bih1, const float* __restrict__ bhh1,
             const float* __restrict__ Wd, const float* __restrict__ bd,
             float* __restrict__ out, char* __restrict__ wsc)
{
    cg::grid_group grid = cg::this_grid();
    const int wg   = blockIdx.x;      // 0..255
    const int g    = wg >> 7;         // kgroup: K-half
    const int c    = wg & 127;        // colgroup: h-cols [c*8, c*8+8)
    const int tid  = threadIdx.x;     // 0..511
    const int r    = tid >> 6;        // rowgroup 0..7: batches [r*16, r*16+16)
    const int lane = tid & 63;
    const int l15  = lane & 15;
    const int quad = lane >> 4;

    _Float16* h0b = (_Float16*)(wsc + H0_OFF);   // [8][128][1024] ring
    _Float16* h1b = (_Float16*)(wsc + H1_OFF);   // [8][128][1024] ring
    char* bar = wsc + BAR_OFF;
    float* part = (float*)(wsc + PART_OFF);
    float* my_part = part + (size_t)(g * 128 + c) * 4096;        // my partial for partner's batches
    float* pr_part = part + (size_t)((1 - g) * 128 + c) * 4096;  // partner's partial for my batches
    unsigned* myflag = (unsigned*)(bar + 8192 + c * 128 + g * 4);
    unsigned* prflag = (unsigned*)(bar + 8192 + c * 128 + (1 - g) * 4);

    extern __shared__ char smem[];
    _Float16* w0l = (_Float16*)(smem);            // [32][648]
    _Float16* w1l = (_Float16*)(smem + 41472);    // [32][1032]
    float*    gs0 = (float*)(smem + 107520);      // [32][132] col-major
    float*    gs1 = (float*)(smem + 124416);      // [32][132]
    float*    prl = (float*)(smem + 141312);      // [2][32][68] staged partner partial
    float*    bs0 = (float*)(smem + 158720);      // [32]
    float*    bs1 = (float*)(smem + 158848);      // [32]

    // ---------- init: stage weight slice (8 cols x K-half) into LDS ----------
    for (int i = tid; i < 32 * 640; i += 512) {
        int n = i / 640, k = i - n * 640;
        int gcol = ((n >> 3) << 10) + (c << 3) + (n & 7);
        float v = (k < NIN) ? Wih0[gcol * NIN + k] : Whh0[gcol * NH + g * 512 + (k - NIN)];
        w0l[n * W0STRIDE + k] = (_Float16)v;
    }
    for (int i = tid; i < 32 * 1024; i += 512) {
        int n = i >> 10, k = i & 1023;
        int gcol = ((n >> 3) << 10) + (c << 3) + (n & 7);
        float v = (k < 512) ? Wih1[gcol * NH + g * 512 + k] : Whh1[gcol * NH + g * 512 + (k - 512)];
        w1l[n * W1STRIDE + k] = (_Float16)v;
    }
    if (tid < 32) {
        int n = tid;
        int gcol = ((n >> 3) << 10) + (c << 3) + (n & 7);
        bs0[n] = bih0[gcol] + bhh0[gcol];
        bs1[n] = bih1[gcol] + bhh1[gcol];
    }

    // ---------- init: zero h rings + barrier/pairflag state ----------
    {
        const int gtid = wg * 512 + tid;
        const int gsz  = 256 * 512;
        float* hz = (float*)wsc;     // both h rings = 4 MiB = 1048576 floats
        for (int i = gtid; i < 1048576; i += gsz) hz[i] = 0.0f;
        if (wg == 0) {
            if (tid < 18) {
                if (tid < 16)       *(unsigned*)(bar + tid * 256) = 0u;
                else if (tid == 16) *(unsigned*)(bar + 4096) = 0u;
                else                *(unsigned*)(bar + 4352) = 0u;
            }
            for (int i = tid; i < 4096; i += 512) *(unsigned*)(bar + 8192 + i * 4) = 0u;
        }
    }
    __builtin_amdgcn_fence(__ATOMIC_RELEASE, "agent");
    grid.sync();
    __builtin_amdgcn_fence(__ATOMIC_ACQUIRE, "agent");

    float c0 = 0.0f, c1 = 0.0f;          // cell state: 1 (b,hcol) pair/thread
    const int bh_   = tid >> 3;          // local batch 0..63
    const int cl_   = tid & 7;           // local h-col 0..7
    const int bact  = g * 64 + bh_;      // owned global batch
    const int hcol  = (c << 3) + cl_;

    // B-fragment row bases in LDS (per nt tile), quad*8 baked in
    const _Float16* bw0[2];  const _Float16* bw1i[2];  const _Float16* bw1h[2];  const _Float16* bx[2];
    #pragma unroll
    for (int nt = 0; nt < 2; ++nt) {
        bw0[nt]  = w0l + (nt * 16 + l15) * W0STRIDE + NIN + quad * 8;  // Whh0 K-half
        bw1i[nt] = w1l + (nt * 16 + l15) * W1STRIDE + quad * 8;        // Wih1 K-half
        bw1h[nt] = bw1i[nt] + 512;                                     // Whh1 K-half
        bx[nt]   = w0l + (nt * 16 + l15) * W0STRIDE + quad * 8;        // x weights (full 128)
    }
    const int aoff = (r * 16 + l15) * NH + g * 512 + quad * 8;         // A-row offset in h arrays

    floatx4 accx0 = {0.f,0.f,0.f,0.f}, accx1 = {0.f,0.f,0.f,0.f};

    // x-part of layer0 gates (h-independent, g==0 WGs only), fp32 x converted on the fly
    auto xpart = [&](int t) {
        floatx4 ax0 = {0.f,0.f,0.f,0.f}, ax1 = {0.f,0.f,0.f,0.f};
        const float* xr = x + (size_t)(r * 16 + l15) * (NT * NIN) + t * NIN + quad * 8;
        #pragma unroll
        for (int j = 0; j < 4; ++j) {
            floatx4 f0 = *(const floatx4*)(xr + j * 32);
            floatx4 f1 = *(const floatx4*)(xr + j * 32 + 4);
            half8 a;
            a[0]=(_Float16)f0[0]; a[1]=(_Float16)f0[1]; a[2]=(_Float16)f0[2]; a[3]=(_Float16)f0[3];
            a[4]=(_Float16)f1[0]; a[5]=(_Float16)f1[1]; a[6]=(_Float16)f1[2]; a[7]=(_Float16)f1[3];
            half8 b0 = *(const half8*)(bx[0] + j * 32);
            half8 b1 = *(const half8*)(bx[1] + j * 32);
            ax0 = __builtin_amdgcn_mfma_f32_16x16x32_f16(a, b0, ax0, 0, 0, 0);
            ax1 = __builtin_amdgcn_mfma_f32_16x16x32_f16(a, b1, ax1, 0, 0, 0);
        }
        accx0 = ax0; accx1 = ax1;
    };

    if (g == 0) xpart(0);   // prologue

    // phase p: computes h0[p] (p<NT) and h1[p-1] (p>=1)
    // ring reads: h0[p-1] -> buf (p+7)&7 ; h1[p-2] -> buf (p+6)&7
    for (int p = 0; p <= NT; ++p) {
        const _Float16* arow_h0 = h0b + (size_t)((p + 7) & 7) * (NB * NH) + aoff;
        const _Float16* arow_h1 = h1b + (size_t)((p + 6) & 7) * (NB * NH) + aoff;

        floatx4 acc0[2]  = { accx0, accx1 };
        floatx4 acc1[2]  = { {0.f,0.f,0.f,0.f}, {0.f,0.f,0.f,0.f} };
        floatx4 acc1b[2] = { {0.f,0.f,0.f,0.f}, {0.f,0.f,0.f,0.f} };

        if (p >= 1 && p < NT) {
            #pragma unroll
            for (int jb = 0; jb < 4; ++jb) {
                half8 a0v[4], a1v[4];
                #pragma unroll
                for (int j = 0; j < 4; ++j) a0v[j] = *(const half8*)(arow_h0 + (jb * 4 + j) * 32);
                #pragma unroll
                for (int j = 0; j < 4; ++j) a1v[j] = *(const half8*)(arow_h1 + (jb * 4 + j) * 32);
                #pragma unroll
                for (int j = 0; j < 4; ++j) {
                    #pragma unroll
                    for (int nt = 0; nt < 2; ++nt) {
                        half8 v0 = *(const half8*)(bw0[nt]  + (jb * 4 + j) * 32);
                        half8 v1 = *(const half8*)(bw1i[nt] + (jb * 4 + j) * 32);
                        half8 v2 = *(const half8*)(bw1h[nt] + (jb * 4 + j) * 32);
                        acc0[nt]  = __builtin_amdgcn_mfma_f32_16x16x32_f16(a0v[j], v0, acc0[nt], 0, 0, 0);
                        acc1[nt]  = __builtin_amdgcn_mfma_f32_16x16x32_f16(a0v[j], v1, acc1[nt], 0, 0, 0);
                        acc1b[nt] = __builtin_amdgcn_mfma_f32_16x16x32_f16(a1v[j], v2, acc1b[nt], 0, 0, 0);
                    }
                }
            }
        } else if (p == NT) {  // layer1 only
            #pragma unroll
            for (int jb = 0; jb < 4; ++jb) {
                half8 a0v[4], a1v[4];
                #pragma unroll
                for (int j = 0; j < 4; ++j) a0v[j] = *(const half8*)(arow_h0 + (jb * 4 + j) * 32);
                #pragma unroll
                for (int j = 0; j < 4; ++j) a1v[j] = *(const half8*)(arow_h1 + (jb * 4 + j) * 32);
                #pragma unroll
                for (int j = 0; j < 4; ++j) {
                    #pragma unroll
                    for (int nt = 0; nt < 2; ++nt) {
                        half8 v1 = *(const half8*)(bw1i[nt] + (jb * 4 + j) * 32);
                        half8 v2 = *(const half8*)(bw1h[nt] + (jb * 4 + j) * 32);
                        acc1[nt]  = __builtin_amdgcn_mfma_f32_16x16x32_f16(a0v[j], v1, acc1[nt], 0, 0, 0);
                        acc1b[nt] = __builtin_amdgcn_mfma_f32_16x16x32_f16(a1v[j], v2, acc1b[nt], 0, 0, 0);
                    }
                }
            }
        }
        // p == 0: h rings are zeros; gates = x-part only
        acc1[0] = acc1[0] + acc1b[0];
        acc1[1] = acc1[1] + acc1b[1];

        // stash K-partial gate tiles (all 128 batches) to LDS, col-major
        #pragma unroll
        for (int nt = 0; nt < 2; ++nt) {
            if (p < NT)  *(floatx4*)&gs0[(nt * 16 + l15) * GSTRIDE + r * 16 + quad * 4] = acc0[nt];
            if (p >= 1)  *(floatx4*)&gs1[(nt * 16 + l15) * GSTRIDE + r * 16 + quad * 4] = acc1[nt];
        }
        __syncthreads();

        // ---- pairwise K-partial exchange: send my partial for PARTNER's batches
        // idx = l*2048 + n*64 + bo  (l=layer, n=gatecol, bo=partner-local batch)
        #pragma unroll
        for (int rep = 0; rep < 8; ++rep) {
            int idx = rep * 512 + tid;
            int l = idx >> 11, rem = idx & 2047;
            int n = rem >> 6, bo = (rem & 63) + (1 - g) * 64;
            float v = l ? gs1[n * GSTRIDE + bo] : gs0[n * GSTRIDE + bo];
            st4_agent(my_part + idx, v);
        }
        __syncthreads();                       // drains vmcnt: partial stores at LLC
        if (tid == 0) {
            __hip_atomic_store(myflag, (unsigned)(p + 1), __ATOMIC_RELAXED, __HIP_MEMORY_SCOPE_AGENT);
            while (__hip_atomic_load(prflag, __ATOMIC_RELAXED, __HIP_MEMORY_SCOPE_AGENT) < (unsigned)(p + 1))
                __builtin_amdgcn_s_sleep(1);
        }
        __syncthreads();                       // partner's partial is at LLC now

        // stage partner partial into LDS (dense agent loads bypass stale L1/L2);
        // LDS dest uses PADDED stride 68 (bank = 4n+bo, conflict-free)
        #pragma unroll
        for (int rep = 0; rep < 8; ++rep) {
            int idx = rep * 512 + tid;
            int l = idx >> 11, rem = idx & 2047;
            int n = rem >> 6, bo = rem & 63;
            prl[l * PRL_L + n * PRLSTRIDE + bo] = ld4_agent(pr_part + idx);
        }
        __syncthreads();

        // activation: this WG owns batches [g*64, g*64+64) for its 8 h-cols
        {
            if (p < NT) {
                float gi = gs0[(cl_)      * GSTRIDE + bact] + prl[(cl_)      * PRLSTRIDE + bh_] + bs0[cl_];
                float gf = gs0[(8 + cl_)  * GSTRIDE + bact] + prl[(8 + cl_)  * PRLSTRIDE + bh_] + bs0[8 + cl_];
                float gg = gs0[(16 + cl_) * GSTRIDE + bact] + prl[(16 + cl_) * PRLSTRIDE + bh_] + bs0[16 + cl_];
                float go = gs0[(24 + cl_) * GSTRIDE + bact] + prl[(24 + cl_) * PRLSTRIDE + bh_] + bs0[24 + cl_];
                c0 = sigm(gf) * c0 + sigm(gi) * tanh_fast(gg);
                float h = sigm(go) * tanh_fast(c0);
                st2_agent(h0b + (size_t)(p & 7) * (NB * NH) + bact * NH + hcol, h);   // h0[p]
            }
            if (p >= 1) {
                float gi = gs1[(cl_)      * GSTRIDE + bact] + prl[PRL_L + (cl_)      * PRLSTRIDE + bh_] + bs1[cl_];
                float gf = gs1[(8 + cl_)  * GSTRIDE + bact] + prl[PRL_L + (8 + cl_)  * PRLSTRIDE + bh_] + bs1[8 + cl_];
                float gg = gs1[(16 + cl_) * GSTRIDE + bact] + prl[PRL_L + (16 + cl_) * PRLSTRIDE + bh_] + bs1[16 + cl_];
                float go = gs1[(24 + cl_) * GSTRIDE + bact] + prl[PRL_L + (24 + cl_) * PRLSTRIDE + bh_] + bs1[24 + cl_];
                c1 = sigm(gf) * c1 + sigm(gi) * tanh_fast(gg);
                float h = sigm(go) * tanh_fast(c1);
                st2_agent(h1b + (size_t)((p + 7) & 7) * (NB * NH) + bact * NH + hcol, h);  // h1[p-1]
            }
        }

        // ---- global barrier with overlap: next x-part hides the spin window
        __syncthreads();                       // drains vmcnt: h-stores at LLC
        if (tid == 0) gbar_arrive(bar, (unsigned)(p + 1), wg);
        if (g == 0 && p + 1 < NT) xpart(p + 1);
        if (tid == 0) gbar_wait(bar, (unsigned)(p + 1));
        __syncthreads();
    }

    // dense head: WG b (<128) computes out[b][0..1] from h1[255] (ring slot 7)
    if (wg < NB) {
        const _Float16* hrow = h1b + (size_t)7 * (NB * NH) + wg * NH;
        float hk0 = (float)hrow[tid * 2];
        float hk1 = (float)hrow[tid * 2 + 1];
        float p0 = hk0 * Wd[tid * 2] + hk1 * Wd[tid * 2 + 1];
        float p1 = hk0 * Wd[NH + tid * 2] + hk1 * Wd[NH + tid * 2 + 1];
        #pragma unroll
        for (int off = 32; off; off >>= 1) {
            p0 += __shfl_down(p0, off);
            p1 += __shfl_down(p1, off);
        }
        float* red = gs0;  // reuse LDS
        if (lane == 0) { red[r * 2] = p0; red[r * 2 + 1] = p1; }
        __syncthreads();
        if (tid < 2) {
            float s = bd[tid];
            #pragma unroll
            for (int w = 0; w < 8; ++w) s += red[w * 2 + tid];
            out[wg * 2 + tid] = tanhf(s);
        }
    }
}

extern "C" void kernel_launch(void* const* d_in, const int* in_sizes, int n_in,
                              void* d_out, int out_size, void* d_ws, size_t ws_size,
                              hipStream_t stream) {
    const float* x    = (const float*)d_in[0];
    const float* Wih0 = (const float*)d_in[1];
    const float* Whh0 = (const float*)d_in[2];
    const float* bih0 = (const float*)d_in[3];
    const float* bhh0 = (const float*)d_in[4];
    const float* Wih1 = (const float*)d_in[5];
    const float* Whh1 = (const float*)d_in[6];
    const float* bih1 = (const float*)d_in[7];
    const float* bhh1 = (const float*)d_in[8];
    const float* Wd   = (const float*)d_in[9];
    const float* bd   = (const float*)d_in[10];
    float* out = (float*)d_out;
    char* ws = (char*)d_ws;

    hipFuncSetAttribute((const void*)lstm_persist,
                        hipFuncAttributeMaxDynamicSharedMemorySize, LDS_BYTES);

    void* kargs[] = { &x, &Wih0, &Whh0, &bih0, &bhh0, &Wih1, &Whh1, &bih1, &bhh1,
                      &Wd, &bd, &out, &ws };
    hipLaunchCooperativeKernel((void*)lstm_persist, dim3(256), dim3(512),
                               kargs, LDS_BYTES, stream);
}

// Round 8
// 3701.936 us; speedup vs baseline: 1.9672x; 1.0328x over previous
//
#include <hip/hip_runtime.h>
#include <hip/hip_fp16.h>
#include <hip/hip_cooperative_groups.h>

namespace cg = cooperative_groups;

typedef _Float16 half8 __attribute__((ext_vector_type(8)));
typedef float floatx4 __attribute__((ext_vector_type(4)));

#define NB 128
#define NT 256
#define NIN 128
#define NH 1024

// ws layout (bytes):
//  h rings: 8-deep (L2-inv only every 8th phase)
//  PART: pairwise K-partial exchange buffers [2 kg][128 cg][2 layers][32 n][64 b] fp32
#define H0_OFF   0u          // 8 x 128*1024 half = 2097152 B
#define H1_OFF   2097152u    // 2097152 B
#define PART_OFF 4194304u    // 2*128*4096 floats = 4194304 B
#define BAR_OFF  8388608u    // 16 group lines @256B, root @4096, flag @4352, pairflags @8192

// LDS layout (bytes):
//  w0l: 32 n x (640+8) half  = 41472            [x(128) | Whh0 K-half(512)]
//  w1l: 32 n x (1024+8) half = 66048  @41472    [Wih1 K-half | Whh1 K-half]
//  gs0: 32 n x 132 float     = 16896  @107520   col-major gate tile (own half only)
//  gs1: 32 n x 132 float     = 16896  @124416
//  bs0/bs1: 32+32 float      = 256    @141312   -> total 141568
//
// STRIDE RULES (R4/R5 2x regression): B-row stride MUST be a multiple of
// 8 halves (16 B) or ds_read_b128 is misaligned and splits into b32/b64
// (~4x LDS ops, 3876 -> 7282 us). 648/1032 halves (== 4 mod 32 words) give
// the minimal free 2-way pattern for the 16-row x quad reads.
//
// R7 restructure: exchange path shortened. Partner-half waves store acc
// registers DIRECTLY to my_part (8B agent atomics) -- no gs stash, no
// cooperative re-read. Activation loads partner partials DIRECTLY from
// pr_part (agent loads) -- no prl LDS staging. 6 syncthreads/phase -> 4.
// (R7 bench: container-level infra failure, no kernel signal; resubmitted
// unchanged for attribution.)
#define W0STRIDE 648
#define W1STRIDE 1032
#define GSTRIDE  132
#define LDS_BYTES 141568

__device__ __forceinline__ float sigm(float x) { return 1.0f / (1.0f + __expf(-x)); }
__device__ __forceinline__ float tanh_fast(float x) { return 1.0f - 2.0f / (__expf(2.0f * x) + 1.0f); }

// agent-scope relaxed stores: write-through past non-coherent XCD L2 to LLC.
// After __syncthreads' vmcnt(0) drain these are globally visible.
__device__ __forceinline__ void st2_agent(_Float16* p, float v) {
    _Float16 hv = (_Float16)v;
    unsigned short u;
    __builtin_memcpy(&u, &hv, 2);
    __hip_atomic_store((unsigned short*)p, u, __ATOMIC_RELAXED, __HIP_MEMORY_SCOPE_AGENT);
}
__device__ __forceinline__ void st8_agent(float* p, float a, float b) {
    float v2[2] = { a, b };
    unsigned long long u;
    __builtin_memcpy(&u, v2, 8);
    __hip_atomic_store((unsigned long long*)p, u, __ATOMIC_RELAXED, __HIP_MEMORY_SCOPE_AGENT);
}
__device__ __forceinline__ float ld4_agent(const float* p) {
    return __hip_atomic_load(p, __ATOMIC_RELAXED, __HIP_MEMORY_SCOPE_AGENT);
}

// Two-level grid barrier: 16 groups x 16 WGs. Ring-aware acquire fences:
// full agent fence (L1+XCD-L2 inv) only every 8th epoch (ring reuse boundary),
// cheap L1-only inv otherwise.
__device__ __forceinline__ void gbar_arrive(char* bar, unsigned epoch, int wg) {
    unsigned* gcnt = (unsigned*)(bar + (wg & 15) * 256);
    unsigned old = __hip_atomic_fetch_add(gcnt, 1u, __ATOMIC_RELAXED, __HIP_MEMORY_SCOPE_AGENT);
    if (old == epoch * 16u - 1u) {
        unsigned* rcnt = (unsigned*)(bar + 4096);
        unsigned rold = __hip_atomic_fetch_add(rcnt, 1u, __ATOMIC_RELAXED, __HIP_MEMORY_SCOPE_AGENT);
        if (rold == epoch * 16u - 1u) {
            unsigned* flag = (unsigned*)(bar + 4352);
            __hip_atomic_store(flag, epoch, __ATOMIC_RELAXED, __HIP_MEMORY_SCOPE_AGENT);
        }
    }
}
__device__ __forceinline__ void gbar_wait(char* bar, unsigned epoch) {
    unsigned* flag = (unsigned*)(bar + 4352);
    while (__hip_atomic_load(flag, __ATOMIC_RELAXED, __HIP_MEMORY_SCOPE_AGENT) < epoch)
        __builtin_amdgcn_s_sleep(1);
    if ((epoch & 7u) == 0u) {
        __builtin_amdgcn_fence(__ATOMIC_ACQUIRE, "agent");
    } else {
        asm volatile("s_waitcnt vmcnt(0)\n\tbuffer_inv sc0" ::: "memory");
    }
}

// K-split across WG pairs: WG (g = wg>>7, c = wg&127) owns 8 h-cols
// [c*8, c*8+8) and K-half [g*512, g*512+512). Partials summed via pairwise
// LLC exchange; activation ownership split by batch half.
__global__ void __launch_bounds__(512, 2)
lstm_persist(const float* __restrict__ x,
             const float* __restrict__ Wih0, const float* __restrict__ Whh0,
             const float* __restrict__ bih0, const float* __restrict__ bhh0,
             const float* __restrict__ Wih1, const float* __restrict__ Whh1,
             const float* __restrict__ bih1, const float* __restrict__ bhh1,
             const float* __restrict__ Wd, const float* __restrict__ bd,
             float* __restrict__ out, char* __restrict__ wsc)
{
    cg::grid_group grid = cg::this_grid();
    const int wg   = blockIdx.x;      // 0..255
    const int g    = wg >> 7;         // kgroup: K-half
    const int c    = wg & 127;        // colgroup: h-cols [c*8, c*8+8)
    const int tid  = threadIdx.x;     // 0..511
    const int r    = tid >> 6;        // rowgroup 0..7: batches [r*16, r*16+16)
    const int lane = tid & 63;
    const int l15  = lane & 15;
    const int quad = lane >> 4;

    _Float16* h0b = (_Float16*)(wsc + H0_OFF);   // [8][128][1024] ring
    _Float16* h1b = (_Float16*)(wsc + H1_OFF);   // [8][128][1024] ring
    char* bar = wsc + BAR_OFF;
    float* part = (float*)(wsc + PART_OFF);
    float* my_part = part + (size_t)(g * 128 + c) * 4096;        // my partial for partner's batches
    float* pr_part = part + (size_t)((1 - g) * 128 + c) * 4096;  // partner's partial for my batches
    unsigned* myflag = (unsigned*)(bar + 8192 + c * 128 + g * 4);
    unsigned* prflag = (unsigned*)(bar + 8192 + c * 128 + (1 - g) * 4);

    extern __shared__ char smem[];
    _Float16* w0l = (_Float16*)(smem);            // [32][648]
    _Float16* w1l = (_Float16*)(smem + 41472);    // [32][1032]
    float*    gs0 = (float*)(smem + 107520);      // [32][132] col-major (own half)
    float*    gs1 = (float*)(smem + 124416);      // [32][132]
    float*    bs0 = (float*)(smem + 141312);      // [32]
    float*    bs1 = (float*)(smem + 141440);      // [32]

    // ---------- init: stage weight slice (8 cols x K-half) into LDS ----------
    for (int i = tid; i < 32 * 640; i += 512) {
        int n = i / 640, k = i - n * 640;
        int gcol = ((n >> 3) << 10) + (c << 3) + (n & 7);
        float v = (k < NIN) ? Wih0[gcol * NIN + k] : Whh0[gcol * NH + g * 512 + (k - NIN)];
        w0l[n * W0STRIDE + k] = (_Float16)v;
    }
    for (int i = tid; i < 32 * 1024; i += 512) {
        int n = i >> 10, k = i & 1023;
        int gcol = ((n >> 3) << 10) + (c << 3) + (n & 7);
        float v = (k < 512) ? Wih1[gcol * NH + g * 512 + k] : Whh1[gcol * NH + g * 512 + (k - 512)];
        w1l[n * W1STRIDE + k] = (_Float16)v;
    }
    if (tid < 32) {
        int n = tid;
        int gcol = ((n >> 3) << 10) + (c << 3) + (n & 7);
        bs0[n] = bih0[gcol] + bhh0[gcol];
        bs1[n] = bih1[gcol] + bhh1[gcol];
    }

    // ---------- init: zero h rings + barrier/pairflag state ----------
    {
        const int gtid = wg * 512 + tid;
        const int gsz  = 256 * 512;
        float* hz = (float*)wsc;     // both h rings = 4 MiB = 1048576 floats
        for (int i = gtid; i < 1048576; i += gsz) hz[i] = 0.0f;
        if (wg == 0) {
            if (tid < 18) {
                if (tid < 16)       *(unsigned*)(bar + tid * 256) = 0u;
                else if (tid == 16) *(unsigned*)(bar + 4096) = 0u;
                else                *(unsigned*)(bar + 4352) = 0u;
            }
            for (int i = tid; i < 4096; i += 512) *(unsigned*)(bar + 8192 + i * 4) = 0u;
        }
    }
    __builtin_amdgcn_fence(__ATOMIC_RELEASE, "agent");
    grid.sync();
    __builtin_amdgcn_fence(__ATOMIC_ACQUIRE, "agent");

    float c0 = 0.0f, c1 = 0.0f;          // cell state: 1 (b,hcol) pair/thread
    const int bh_   = tid >> 3;          // local batch 0..63
    const int cl_   = tid & 7;           // local h-col 0..7
    const int bact  = g * 64 + bh_;      // owned global batch
    const int hcol  = (c << 3) + cl_;
    const int ownhalf = ((r >> 2) == g); // this wave's batches are in own act half
    const int bo_base = r * 16 + quad * 4 - (1 - g) * 64;  // partner-local batch base

    // B-fragment row bases in LDS (per nt tile), quad*8 baked in
    const _Float16* bw0[2];  const _Float16* bw1i[2];  const _Float16* bw1h[2];  const _Float16* bx[2];
    #pragma unroll
    for (int nt = 0; nt < 2; ++nt) {
        bw0[nt]  = w0l + (nt * 16 + l15) * W0STRIDE + NIN + quad * 8;  // Whh0 K-half
        bw1i[nt] = w1l + (nt * 16 + l15) * W1STRIDE + quad * 8;        // Wih1 K-half
        bw1h[nt] = bw1i[nt] + 512;                                     // Whh1 K-half
        bx[nt]   = w0l + (nt * 16 + l15) * W0STRIDE + quad * 8;        // x weights (full 128)
    }
    const int aoff = (r * 16 + l15) * NH + g * 512 + quad * 8;         // A-row offset in h arrays

    floatx4 accx0 = {0.f,0.f,0.f,0.f}, accx1 = {0.f,0.f,0.f,0.f};

    // x-part of layer0 gates (h-independent, g==0 WGs only), fp32 x converted on the fly
    auto xpart = [&](int t) {
        floatx4 ax0 = {0.f,0.f,0.f,0.f}, ax1 = {0.f,0.f,0.f,0.f};
        const float* xr = x + (size_t)(r * 16 + l15) * (NT * NIN) + t * NIN + quad * 8;
        #pragma unroll
        for (int j = 0; j < 4; ++j) {
            floatx4 f0 = *(const floatx4*)(xr + j * 32);
            floatx4 f1 = *(const floatx4*)(xr + j * 32 + 4);
            half8 a;
            a[0]=(_Float16)f0[0]; a[1]=(_Float16)f0[1]; a[2]=(_Float16)f0[2]; a[3]=(_Float16)f0[3];
            a[4]=(_Float16)f1[0]; a[5]=(_Float16)f1[1]; a[6]=(_Float16)f1[2]; a[7]=(_Float16)f1[3];
            half8 b0 = *(const half8*)(bx[0] + j * 32);
            half8 b1 = *(const half8*)(bx[1] + j * 32);
            ax0 = __builtin_amdgcn_mfma_f32_16x16x32_f16(a, b0, ax0, 0, 0, 0);
            ax1 = __builtin_amdgcn_mfma_f32_16x16x32_f16(a, b1, ax1, 0, 0, 0);
        }
        accx0 = ax0; accx1 = ax1;
    };

    if (g == 0) xpart(0);   // prologue

    // phase p: computes h0[p] (p<NT) and h1[p-1] (p>=1)
    // ring reads: h0[p-1] -> buf (p+7)&7 ; h1[p-2] -> buf (p+6)&7
    for (int p = 0; p <= NT; ++p) {
        const _Float16* arow_h0 = h0b + (size_t)((p + 7) & 7) * (NB * NH) + aoff;
        const _Float16* arow_h1 = h1b + (size_t)((p + 6) & 7) * (NB * NH) + aoff;

        floatx4 acc0[2]  = { accx0, accx1 };
        floatx4 acc1[2]  = { {0.f,0.f,0.f,0.f}, {0.f,0.f,0.f,0.f} };
        floatx4 acc1b[2] = { {0.f,0.f,0.f,0.f}, {0.f,0.f,0.f,0.f} };

        if (p >= 1 && p < NT) {
            #pragma unroll
            for (int jb = 0; jb < 4; ++jb) {
                half8 a0v[4], a1v[4];
                #pragma unroll
                for (int j = 0; j < 4; ++j) a0v[j] = *(const half8*)(arow_h0 + (jb * 4 + j) * 32);
                #pragma unroll
                for (int j = 0; j < 4; ++j) a1v[j] = *(const half8*)(arow_h1 + (jb * 4 + j) * 32);
                #pragma unroll
                for (int j = 0; j < 4; ++j) {
                    #pragma unroll
                    for (int nt = 0; nt < 2; ++nt) {
                        half8 v0 = *(const half8*)(bw0[nt]  + (jb * 4 + j) * 32);
                        half8 v1 = *(const half8*)(bw1i[nt] + (jb * 4 + j) * 32);
                        half8 v2 = *(const half8*)(bw1h[nt] + (jb * 4 + j) * 32);
                        acc0[nt]  = __builtin_amdgcn_mfma_f32_16x16x32_f16(a0v[j], v0, acc0[nt], 0, 0, 0);
                        acc1[nt]  = __builtin_amdgcn_mfma_f32_16x16x32_f16(a0v[j], v1, acc1[nt], 0, 0, 0);
                        acc1b[nt] = __builtin_amdgcn_mfma_f32_16x16x32_f16(a1v[j], v2, acc1b[nt], 0, 0, 0);
                    }
                }
            }
        } else if (p == NT) {  // layer1 only
            #pragma unroll
            for (int jb = 0; jb < 4; ++jb) {
                half8 a0v[4], a1v[4];
                #pragma unroll
                for (int j = 0; j < 4; ++j) a0v[j] = *(const half8*)(arow_h0 + (jb * 4 + j) * 32);
                #pragma unroll
                for (int j = 0; j < 4; ++j) a1v[j] = *(const half8*)(arow_h1 + (jb * 4 + j) * 32);
                #pragma unroll
                for (int j = 0; j < 4; ++j) {
                    #pragma unroll
                    for (int nt = 0; nt < 2; ++nt) {
                        half8 v1 = *(const half8*)(bw1i[nt] + (jb * 4 + j) * 32);
                        half8 v2 = *(const half8*)(bw1h[nt] + (jb * 4 + j) * 32);
                        acc1[nt]  = __builtin_amdgcn_mfma_f32_16x16x32_f16(a0v[j], v1, acc1[nt], 0, 0, 0);
                        acc1b[nt] = __builtin_amdgcn_mfma_f32_16x16x32_f16(a1v[j], v2, acc1b[nt], 0, 0, 0);
                    }
                }
            }
        }
        // p == 0: h rings are zeros; gates = x-part only
        acc1[0] = acc1[0] + acc1b[0];
        acc1[1] = acc1[1] + acc1b[1];

        // ---- partial hand-off: own-half waves stash to LDS for local act;
        // ---- partner-half waves store registers DIRECTLY to my_part (LLC).
        if (ownhalf) {
            #pragma unroll
            for (int nt = 0; nt < 2; ++nt) {
                if (p < NT)  *(floatx4*)&gs0[(nt * 16 + l15) * GSTRIDE + r * 16 + quad * 4] = acc0[nt];
                if (p >= 1)  *(floatx4*)&gs1[(nt * 16 + l15) * GSTRIDE + r * 16 + quad * 4] = acc1[nt];
            }
        } else {
            #pragma unroll
            for (int nt = 0; nt < 2; ++nt) {
                float* d0 = my_part + (nt * 16 + l15) * 64 + bo_base;          // layer0
                st8_agent(d0,     acc0[nt][0], acc0[nt][1]);
                st8_agent(d0 + 2, acc0[nt][2], acc0[nt][3]);
                float* d1 = my_part + 2048 + (nt * 16 + l15) * 64 + bo_base;   // layer1
                st8_agent(d1,     acc1[nt][0], acc1[nt][1]);
                st8_agent(d1 + 2, acc1[nt][2], acc1[nt][3]);
            }
        }
        __syncthreads();                       // LDS visible + vmcnt drain: partials at LLC
        if (tid == 0) {
            __hip_atomic_store(myflag, (unsigned)(p + 1), __ATOMIC_RELAXED, __HIP_MEMORY_SCOPE_AGENT);
            while (__hip_atomic_load(prflag, __ATOMIC_RELAXED, __HIP_MEMORY_SCOPE_AGENT) < (unsigned)(p + 1))
                __builtin_amdgcn_s_sleep(1);
        }
        __syncthreads();                       // partner's partial is at LLC now

        // activation: this WG owns batches [g*64, g*64+64) for its 8 h-cols.
        // Partner partials loaded DIRECTLY (agent loads bypass stale L1/L2).
        {
            float q0 = 0.f, q1 = 0.f, q2 = 0.f, q3 = 0.f;
            float u0 = 0.f, u1 = 0.f, u2 = 0.f, u3 = 0.f;
            if (p < NT) {
                q0 = ld4_agent(pr_part + (cl_)      * 64 + bh_);
                q1 = ld4_agent(pr_part + (8 + cl_)  * 64 + bh_);
                q2 = ld4_agent(pr_part + (16 + cl_) * 64 + bh_);
                q3 = ld4_agent(pr_part + (24 + cl_) * 64 + bh_);
            }
            if (p >= 1) {
                u0 = ld4_agent(pr_part + 2048 + (cl_)      * 64 + bh_);
                u1 = ld4_agent(pr_part + 2048 + (8 + cl_)  * 64 + bh_);
                u2 = ld4_agent(pr_part + 2048 + (16 + cl_) * 64 + bh_);
                u3 = ld4_agent(pr_part + 2048 + (24 + cl_) * 64 + bh_);
            }
            if (p < NT) {
                float gi = gs0[(cl_)      * GSTRIDE + bact] + q0 + bs0[cl_];
                float gf = gs0[(8 + cl_)  * GSTRIDE + bact] + q1 + bs0[8 + cl_];
                float gg = gs0[(16 + cl_) * GSTRIDE + bact] + q2 + bs0[16 + cl_];
                float go = gs0[(24 + cl_) * GSTRIDE + bact] + q3 + bs0[24 + cl_];
                c0 = sigm(gf) * c0 + sigm(gi) * tanh_fast(gg);
                float h = sigm(go) * tanh_fast(c0);
                st2_agent(h0b + (size_t)(p & 7) * (NB * NH) + bact * NH + hcol, h);   // h0[p]
            }
            if (p >= 1) {
                float gi = gs1[(cl_)      * GSTRIDE + bact] + u0 + bs1[cl_];
                float gf = gs1[(8 + cl_)  * GSTRIDE + bact] + u1 + bs1[8 + cl_];
                float gg = gs1[(16 + cl_) * GSTRIDE + bact] + u2 + bs1[16 + cl_];
                float go = gs1[(24 + cl_) * GSTRIDE + bact] + u3 + bs1[24 + cl_];
                c1 = sigm(gf) * c1 + sigm(gi) * tanh_fast(gg);
                float h = sigm(go) * tanh_fast(c1);
                st2_agent(h1b + (size_t)((p + 7) & 7) * (NB * NH) + bact * NH + hcol, h);  // h1[p-1]
            }
        }

        // ---- global barrier with overlap: next x-part hides the spin window
        __syncthreads();                       // drains vmcnt: h-stores at LLC
        if (tid == 0) gbar_arrive(bar, (unsigned)(p + 1), wg);
        if (g == 0 && p + 1 < NT) xpart(p + 1);
        if (tid == 0) gbar_wait(bar, (unsigned)(p + 1));
        __syncthreads();
    }

    // dense head: WG b (<128) computes out[b][0..1] from h1[255] (ring slot 7)
    if (wg < NB) {
        const _Float16* hrow = h1b + (size_t)7 * (NB * NH) + wg * NH;
        float hk0 = (float)hrow[tid * 2];
        float hk1 = (float)hrow[tid * 2 + 1];
        float p0 = hk0 * Wd[tid * 2] + hk1 * Wd[tid * 2 + 1];
        float p1 = hk0 * Wd[NH + tid * 2] + hk1 * Wd[NH + tid * 2 + 1];
        #pragma unroll
        for (int off = 32; off; off >>= 1) {
            p0 += __shfl_down(p0, off);
            p1 += __shfl_down(p1, off);
        }
        float* red = gs0;  // reuse LDS
        if (lane == 0) { red[r * 2] = p0; red[r * 2 + 1] = p1; }
        __syncthreads();
        if (tid < 2) {
            float s = bd[tid];
            #pragma unroll
            for (int w = 0; w < 8; ++w) s += red[w * 2 + tid];
            out[wg * 2 + tid] = tanhf(s);
        }
    }
}

extern "C" void kernel_launch(void* const* d_in, const int* in_sizes, int n_in,
                              void* d_out, int out_size, void* d_ws, size_t ws_size,
                              hipStream_t stream) {
    const float* x    = (const float*)d_in[0];
    const float* Wih0 = (const float*)d_in[1];
    const float* Whh0 = (const float*)d_in[2];
    const float* bih0 = (const float*)d_in[3];
    const float* bhh0 = (const float*)d_in[4];
    const float* Wih1 = (const float*)d_in[5];
    const float* Whh1 = (const float*)d_in[6];
    const float* bih1 = (const float*)d_in[7];
    const float* bhh1 = (const float*)d_in[8];
    const float* Wd   = (const float*)d_in[9];
    const float* bd   = (const float*)d_in[10];
    float* out = (float*)d_out;
    char* ws = (char*)d_ws;

    hipFuncSetAttribute((const void*)lstm_persist,
                        hipFuncAttributeMaxDynamicSharedMemorySize, LDS_BYTES);

    void* kargs[] = { &x, &Wih0, &Whh0, &bih0, &bhh0, &Wih1, &Whh1, &bih1, &bhh1,
                      &Wd, &bd, &out, &ws };
    hipLaunchCooperativeKernel((void*)lstm_persist, dim3(256), dim3(512),
                               kargs, LDS_BYTES, stream);
}

// Round 9
// 3387.033 us; speedup vs baseline: 2.1501x; 1.0930x over previous
//
#include <hip/hip_runtime.h>
#include <hip/hip_fp16.h>
#include <hip/hip_cooperative_groups.h>

namespace cg = cooperative_groups;

typedef _Float16 half8 __attribute__((ext_vector_type(8)));
typedef float floatx4 __attribute__((ext_vector_type(4)));

#define NB 128
#define NT 256
#define NIN 128
#define NH 1024

// ws layout (bytes):
//  h rings: 8-deep (L2-inv only every 8th phase)
//  PART: pairwise K-partial exchange buffers, TRANSPOSED layout (R9):
//        [2 kg][128 cg][2 layers][64 bo][8 cl][4 gate] fp32
//        -> activation reads 4 contiguous gates per thread (2x ld8, coalesced)
#define H0_OFF   0u          // 8 x 128*1024 half = 2097152 B
#define H1_OFF   2097152u    // 2097152 B
#define PART_OFF 4194304u    // 2*128*4096 floats = 4194304 B
#define BAR_OFF  8388608u    // 16 group lines @256B, root @4096, flag @4352, pairflags @8192

// LDS layout (bytes):
//  w0l: 32 n x (640+8) half  = 41472            [x(128) | Whh0 K-half(512)]
//  w1l: 32 n x (1024+8) half = 66048  @41472    [Wih1 K-half | Whh1 K-half]
//  gs0: 32 n x 132 float     = 16896  @107520   col-major gate tile (own half only)
//  gs1: 32 n x 132 float     = 16896  @124416
//  bs0/bs1: 32+32 float      = 256    @141312   -> total 141568
//
// STRIDE RULES (R4/R5 2x regression): B-row stride MUST be a multiple of
// 8 halves (16 B) or ds_read_b128 is misaligned and splits into b32/b64
// (~4x LDS ops, 3876 -> 7282 us). 648/1032 halves (== 4 mod 32 words) give
// the minimal free 2-way pattern for the 16-row x quad reads.
//
// R9: (1) xpart K-split across the pair: g==0 computes x[:,0:64], g==1
// x[:,64:128] -- balances the gbar spin-window work (g==1 previously idled)
// and halves per-WG x read traffic; exchange already sums the halves.
// (2) PART transposed to [bo][cl][gate]: act loads 4 contiguous gates
// (2x 8B agent loads/layer, wave-dense 1KB) instead of 8 scattered 4B.
#define W0STRIDE 648
#define W1STRIDE 1032
#define GSTRIDE  132
#define LDS_BYTES 141568

__device__ __forceinline__ float sigm(float x) { return 1.0f / (1.0f + __expf(-x)); }
__device__ __forceinline__ float tanh_fast(float x) { return 1.0f - 2.0f / (__expf(2.0f * x) + 1.0f); }

// agent-scope relaxed stores: write-through past non-coherent XCD L2 to LLC.
// After __syncthreads' vmcnt(0) drain these are globally visible.
__device__ __forceinline__ void st2_agent(_Float16* p, float v) {
    _Float16 hv = (_Float16)v;
    unsigned short u;
    __builtin_memcpy(&u, &hv, 2);
    __hip_atomic_store((unsigned short*)p, u, __ATOMIC_RELAXED, __HIP_MEMORY_SCOPE_AGENT);
}
__device__ __forceinline__ void st4_agent(float* p, float v) {
    __hip_atomic_store(p, v, __ATOMIC_RELAXED, __HIP_MEMORY_SCOPE_AGENT);
}
__device__ __forceinline__ void ld8_agent(const float* p, float* a, float* b) {
    unsigned long long u = __hip_atomic_load((const unsigned long long*)p,
                                             __ATOMIC_RELAXED, __HIP_MEMORY_SCOPE_AGENT);
    float v2[2];
    __builtin_memcpy(v2, &u, 8);
    *a = v2[0]; *b = v2[1];
}

// Two-level grid barrier: 16 groups x 16 WGs. Ring-aware acquire fences:
// full agent fence (L1+XCD-L2 inv) only every 8th epoch (ring reuse boundary),
// cheap L1-only inv otherwise.
__device__ __forceinline__ void gbar_arrive(char* bar, unsigned epoch, int wg) {
    unsigned* gcnt = (unsigned*)(bar + (wg & 15) * 256);
    unsigned old = __hip_atomic_fetch_add(gcnt, 1u, __ATOMIC_RELAXED, __HIP_MEMORY_SCOPE_AGENT);
    if (old == epoch * 16u - 1u) {
        unsigned* rcnt = (unsigned*)(bar + 4096);
        unsigned rold = __hip_atomic_fetch_add(rcnt, 1u, __ATOMIC_RELAXED, __HIP_MEMORY_SCOPE_AGENT);
        if (rold == epoch * 16u - 1u) {
            unsigned* flag = (unsigned*)(bar + 4352);
            __hip_atomic_store(flag, epoch, __ATOMIC_RELAXED, __HIP_MEMORY_SCOPE_AGENT);
        }
    }
}
__device__ __forceinline__ void gbar_wait(char* bar, unsigned epoch) {
    unsigned* flag = (unsigned*)(bar + 4352);
    while (__hip_atomic_load(flag, __ATOMIC_RELAXED, __HIP_MEMORY_SCOPE_AGENT) < epoch)
        __builtin_amdgcn_s_sleep(1);
    if ((epoch & 7u) == 0u) {
        __builtin_amdgcn_fence(__ATOMIC_ACQUIRE, "agent");
    } else {
        asm volatile("s_waitcnt vmcnt(0)\n\tbuffer_inv sc0" ::: "memory");
    }
}

// K-split across WG pairs: WG (g = wg>>7, c = wg&127) owns 8 h-cols
// [c*8, c*8+8) and K-half [g*512, g*512+512). Partials summed via pairwise
// LLC exchange; activation ownership split by batch half.
__global__ void __launch_bounds__(512, 2)
lstm_persist(const float* __restrict__ x,
             const float* __restrict__ Wih0, const float* __restrict__ Whh0,
             const float* __restrict__ bih0, const float* __restrict__ bhh0,
             const float* __restrict__ Wih1, const float* __restrict__ Whh1,
             const float* __restrict__ bih1, const float* __restrict__ bhh1,
             const float* __restrict__ Wd, const float* __restrict__ bd,
             float* __restrict__ out, char* __restrict__ wsc)
{
    cg::grid_group grid = cg::this_grid();
    const int wg   = blockIdx.x;      // 0..255
    const int g    = wg >> 7;         // kgroup: K-half
    const int c    = wg & 127;        // colgroup: h-cols [c*8, c*8+8)
    const int tid  = threadIdx.x;     // 0..511
    const int r    = tid >> 6;        // rowgroup 0..7: batches [r*16, r*16+16)
    const int lane = tid & 63;
    const int l15  = lane & 15;
    const int quad = lane >> 4;

    _Float16* h0b = (_Float16*)(wsc + H0_OFF);   // [8][128][1024] ring
    _Float16* h1b = (_Float16*)(wsc + H1_OFF);   // [8][128][1024] ring
    char* bar = wsc + BAR_OFF;
    float* part = (float*)(wsc + PART_OFF);
    float* my_part = part + (size_t)(g * 128 + c) * 4096;        // my partial for partner's batches
    float* pr_part = part + (size_t)((1 - g) * 128 + c) * 4096;  // partner's partial for my batches
    unsigned* myflag = (unsigned*)(bar + 8192 + c * 128 + g * 4);
    unsigned* prflag = (unsigned*)(bar + 8192 + c * 128 + (1 - g) * 4);

    extern __shared__ char smem[];
    _Float16* w0l = (_Float16*)(smem);            // [32][648]
    _Float16* w1l = (_Float16*)(smem + 41472);    // [32][1032]
    float*    gs0 = (float*)(smem + 107520);      // [32][132] col-major (own half)
    float*    gs1 = (float*)(smem + 124416);      // [32][132]
    float*    bs0 = (float*)(smem + 141312);      // [32]
    float*    bs1 = (float*)(smem + 141440);      // [32]

    // ---------- init: stage weight slice (8 cols x K-half) into LDS ----------
    for (int i = tid; i < 32 * 640; i += 512) {
        int n = i / 640, k = i - n * 640;
        int gcol = ((n >> 3) << 10) + (c << 3) + (n & 7);
        float v = (k < NIN) ? Wih0[gcol * NIN + k] : Whh0[gcol * NH + g * 512 + (k - NIN)];
        w0l[n * W0STRIDE + k] = (_Float16)v;
    }
    for (int i = tid; i < 32 * 1024; i += 512) {
        int n = i >> 10, k = i & 1023;
        int gcol = ((n >> 3) << 10) + (c << 3) + (n & 7);
        float v = (k < 512) ? Wih1[gcol * NH + g * 512 + k] : Whh1[gcol * NH + g * 512 + (k - 512)];
        w1l[n * W1STRIDE + k] = (_Float16)v;
    }
    if (tid < 32) {
        int n = tid;
        int gcol = ((n >> 3) << 10) + (c << 3) + (n & 7);
        bs0[n] = bih0[gcol] + bhh0[gcol];
        bs1[n] = bih1[gcol] + bhh1[gcol];
    }

    // ---------- init: zero h rings + barrier/pairflag state ----------
    {
        const int gtid = wg * 512 + tid;
        const int gsz  = 256 * 512;
        float* hz = (float*)wsc;     // both h rings = 4 MiB = 1048576 floats
        for (int i = gtid; i < 1048576; i += gsz) hz[i] = 0.0f;
        if (wg == 0) {
            if (tid < 18) {
                if (tid < 16)       *(unsigned*)(bar + tid * 256) = 0u;
                else if (tid == 16) *(unsigned*)(bar + 4096) = 0u;
                else                *(unsigned*)(bar + 4352) = 0u;
            }
            for (int i = tid; i < 4096; i += 512) *(unsigned*)(bar + 8192 + i * 4) = 0u;
        }
    }
    __builtin_amdgcn_fence(__ATOMIC_RELEASE, "agent");
    grid.sync();
    __builtin_amdgcn_fence(__ATOMIC_ACQUIRE, "agent");

    float c0 = 0.0f, c1 = 0.0f;          // cell state: 1 (b,hcol) pair/thread
    const int bh_   = tid >> 3;          // local batch 0..63
    const int cl_   = tid & 7;           // local h-col 0..7
    const int bact  = g * 64 + bh_;      // owned global batch
    const int hcol  = (c << 3) + cl_;
    const int ownhalf = ((r >> 2) == g); // this wave's batches are in own act half
    const int bo_base = r * 16 + quad * 4 - (1 - g) * 64;  // partner-local batch base
    const int nlo = l15 & 7;             // cl part of n
    const int nhi = l15 >> 3;            // gate LSB part of n

    // B-fragment row bases in LDS (per nt tile), quad*8 baked in
    const _Float16* bw0[2];  const _Float16* bw1i[2];  const _Float16* bw1h[2];  const _Float16* bx[2];
    #pragma unroll
    for (int nt = 0; nt < 2; ++nt) {
        bw0[nt]  = w0l + (nt * 16 + l15) * W0STRIDE + NIN + quad * 8;  // Whh0 K-half
        bw1i[nt] = w1l + (nt * 16 + l15) * W1STRIDE + quad * 8;        // Wih1 K-half
        bw1h[nt] = bw1i[nt] + 512;                                     // Whh1 K-half
        bx[nt]   = w0l + (nt * 16 + l15) * W0STRIDE + g * 64 + quad * 8;  // x weights, this pair-half
    }
    const int aoff = (r * 16 + l15) * NH + g * 512 + quad * 8;         // A-row offset in h arrays

    floatx4 accx0 = {0.f,0.f,0.f,0.f}, accx1 = {0.f,0.f,0.f,0.f};

    // x-part of layer0 gates for this WG's x K-half [g*64, g*64+64):
    // BOTH pair members compute their half (R9); exchange sums them.
    auto xpart = [&](int t) {
        floatx4 ax0 = {0.f,0.f,0.f,0.f}, ax1 = {0.f,0.f,0.f,0.f};
        const float* xr = x + (size_t)(r * 16 + l15) * (NT * NIN) + t * NIN + g * 64 + quad * 8;
        #pragma unroll
        for (int j = 0; j < 2; ++j) {
            floatx4 f0 = *(const floatx4*)(xr + j * 32);
            floatx4 f1 = *(const floatx4*)(xr + j * 32 + 4);
            half8 a;
            a[0]=(_Float16)f0[0]; a[1]=(_Float16)f0[1]; a[2]=(_Float16)f0[2]; a[3]=(_Float16)f0[3];
            a[4]=(_Float16)f1[0]; a[5]=(_Float16)f1[1]; a[6]=(_Float16)f1[2]; a[7]=(_Float16)f1[3];
            half8 b0 = *(const half8*)(bx[0] + j * 32);
            half8 b1 = *(const half8*)(bx[1] + j * 32);
            ax0 = __builtin_amdgcn_mfma_f32_16x16x32_f16(a, b0, ax0, 0, 0, 0);
            ax1 = __builtin_amdgcn_mfma_f32_16x16x32_f16(a, b1, ax1, 0, 0, 0);
        }
        accx0 = ax0; accx1 = ax1;
    };

    xpart(0);   // prologue (both pair halves)

    // phase p: computes h0[p] (p<NT) and h1[p-1] (p>=1)
    // ring reads: h0[p-1] -> buf (p+7)&7 ; h1[p-2] -> buf (p+6)&7
    for (int p = 0; p <= NT; ++p) {
        const _Float16* arow_h0 = h0b + (size_t)((p + 7) & 7) * (NB * NH) + aoff;
        const _Float16* arow_h1 = h1b + (size_t)((p + 6) & 7) * (NB * NH) + aoff;

        floatx4 acc0[2]  = { accx0, accx1 };
        floatx4 acc1[2]  = { {0.f,0.f,0.f,0.f}, {0.f,0.f,0.f,0.f} };
        floatx4 acc1b[2] = { {0.f,0.f,0.f,0.f}, {0.f,0.f,0.f,0.f} };

        if (p >= 1 && p < NT) {
            #pragma unroll
            for (int jb = 0; jb < 4; ++jb) {
                half8 a0v[4], a1v[4];
                #pragma unroll
                for (int j = 0; j < 4; ++j) a0v[j] = *(const half8*)(arow_h0 + (jb * 4 + j) * 32);
                #pragma unroll
                for (int j = 0; j < 4; ++j) a1v[j] = *(const half8*)(arow_h1 + (jb * 4 + j) * 32);
                #pragma unroll
                for (int j = 0; j < 4; ++j) {
                    #pragma unroll
                    for (int nt = 0; nt < 2; ++nt) {
                        half8 v0 = *(const half8*)(bw0[nt]  + (jb * 4 + j) * 32);
                        half8 v1 = *(const half8*)(bw1i[nt] + (jb * 4 + j) * 32);
                        half8 v2 = *(const half8*)(bw1h[nt] + (jb * 4 + j) * 32);
                        acc0[nt]  = __builtin_amdgcn_mfma_f32_16x16x32_f16(a0v[j], v0, acc0[nt], 0, 0, 0);
                        acc1[nt]  = __builtin_amdgcn_mfma_f32_16x16x32_f16(a0v[j], v1, acc1[nt], 0, 0, 0);
                        acc1b[nt] = __builtin_amdgcn_mfma_f32_16x16x32_f16(a1v[j], v2, acc1b[nt], 0, 0, 0);
                    }
                }
            }
        } else if (p == NT) {  // layer1 only
            #pragma unroll
            for (int jb = 0; jb < 4; ++jb) {
                half8 a0v[4], a1v[4];
                #pragma unroll
                for (int j = 0; j < 4; ++j) a0v[j] = *(const half8*)(arow_h0 + (jb * 4 + j) * 32);
                #pragma unroll
                for (int j = 0; j < 4; ++j) a1v[j] = *(const half8*)(arow_h1 + (jb * 4 + j) * 32);
                #pragma unroll
                for (int j = 0; j < 4; ++j) {
                    #pragma unroll
                    for (int nt = 0; nt < 2; ++nt) {
                        half8 v1 = *(const half8*)(bw1i[nt] + (jb * 4 + j) * 32);
                        half8 v2 = *(const half8*)(bw1h[nt] + (jb * 4 + j) * 32);
                        acc1[nt]  = __builtin_amdgcn_mfma_f32_16x16x32_f16(a0v[j], v1, acc1[nt], 0, 0, 0);
                        acc1b[nt] = __builtin_amdgcn_mfma_f32_16x16x32_f16(a1v[j], v2, acc1b[nt], 0, 0, 0);
                    }
                }
            }
        }
        // p == 0: h rings are zeros; gates = x-part only
        acc1[0] = acc1[0] + acc1b[0];
        acc1[1] = acc1[1] + acc1b[1];

        // ---- partial hand-off: own-half waves stash to LDS for local act;
        // ---- partner-half waves store registers DIRECTLY to my_part (LLC),
        // ---- TRANSPOSED: addr = bo*32 + cl*4 + gate  (n = gate*8+cl,
        // ---- n = nt*16+l15 -> cl = l15&7, gate = 2*nt + (l15>>3)).
        if (ownhalf) {
            #pragma unroll
            for (int nt = 0; nt < 2; ++nt) {
                if (p < NT)  *(floatx4*)&gs0[(nt * 16 + l15) * GSTRIDE + r * 16 + quad * 4] = acc0[nt];
                if (p >= 1)  *(floatx4*)&gs1[(nt * 16 + l15) * GSTRIDE + r * 16 + quad * 4] = acc1[nt];
            }
        } else {
            #pragma unroll
            for (int nt = 0; nt < 2; ++nt) {
                const int goff = nlo * 4 + 2 * nt + nhi;
                #pragma unroll
                for (int i = 0; i < 4; ++i) {
                    st4_agent(my_part + (bo_base + i) * 32 + goff,        acc0[nt][i]);  // layer0
                    st4_agent(my_part + 2048 + (bo_base + i) * 32 + goff, acc1[nt][i]);  // layer1
                }
            }
        }
        __syncthreads();                       // LDS visible + vmcnt drain: partials at LLC
        if (tid == 0) {
            __hip_atomic_store(myflag, (unsigned)(p + 1), __ATOMIC_RELAXED, __HIP_MEMORY_SCOPE_AGENT);
            while (__hip_atomic_load(prflag, __ATOMIC_RELAXED, __HIP_MEMORY_SCOPE_AGENT) < (unsigned)(p + 1))
                __builtin_amdgcn_s_sleep(1);
        }
        __syncthreads();                       // partner's partial is at LLC now

        // activation: this WG owns batches [g*64, g*64+64) for its 8 h-cols.
        // Partner partials: 4 contiguous gates/thread, 2x 8B agent loads/layer.
        {
            float q0 = 0.f, q1 = 0.f, q2 = 0.f, q3 = 0.f;
            float u0 = 0.f, u1 = 0.f, u2 = 0.f, u3 = 0.f;
            const float* prbase = pr_part + bh_ * 32 + cl_ * 4;
            if (p < NT) {
                ld8_agent(prbase,     &q0, &q1);
                ld8_agent(prbase + 2, &q2, &q3);
            }
            if (p >= 1) {
                ld8_agent(prbase + 2048,     &u0, &u1);
                ld8_agent(prbase + 2048 + 2, &u2, &u3);
            }
            if (p < NT) {
                float gi = gs0[(cl_)      * GSTRIDE + bact] + q0 + bs0[cl_];
                float gf = gs0[(8 + cl_)  * GSTRIDE + bact] + q1 + bs0[8 + cl_];
                float gg = gs0[(16 + cl_) * GSTRIDE + bact] + q2 + bs0[16 + cl_];
                float go = gs0[(24 + cl_) * GSTRIDE + bact] + q3 + bs0[24 + cl_];
                c0 = sigm(gf) * c0 + sigm(gi) * tanh_fast(gg);
                float h = sigm(go) * tanh_fast(c0);
                st2_agent(h0b + (size_t)(p & 7) * (NB * NH) + bact * NH + hcol, h);   // h0[p]
            }
            if (p >= 1) {
                float gi = gs1[(cl_)      * GSTRIDE + bact] + u0 + bs1[cl_];
                float gf = gs1[(8 + cl_)  * GSTRIDE + bact] + u1 + bs1[8 + cl_];
                float gg = gs1[(16 + cl_) * GSTRIDE + bact] + u2 + bs1[16 + cl_];
                float go = gs1[(24 + cl_) * GSTRIDE + bact] + u3 + bs1[24 + cl_];
                c1 = sigm(gf) * c1 + sigm(gi) * tanh_fast(gg);
                float h = sigm(go) * tanh_fast(c1);
                st2_agent(h1b + (size_t)((p + 7) & 7) * (NB * NH) + bact * NH + hcol, h);  // h1[p-1]
            }
        }

        // ---- global barrier with overlap: next x-part hides the spin window
        __syncthreads();                       // drains vmcnt: h-stores + partial-reads done
        if (tid == 0) gbar_arrive(bar, (unsigned)(p + 1), wg);
        if (p + 1 < NT) xpart(p + 1);          // both pair halves work the spin window
        if (tid == 0) gbar_wait(bar, (unsigned)(p + 1));
        __syncthreads();
    }

    // dense head: WG b (<128) computes out[b][0..1] from h1[255] (ring slot 7)
    if (wg < NB) {
        const _Float16* hrow = h1b + (size_t)7 * (NB * NH) + wg * NH;
        float hk0 = (float)hrow[tid * 2];
        float hk1 = (float)hrow[tid * 2 + 1];
        float p0 = hk0 * Wd[tid * 2] + hk1 * Wd[tid * 2 + 1];
        float p1 = hk0 * Wd[NH + tid * 2] + hk1 * Wd[NH + tid * 2 + 1];
        #pragma unroll
        for (int off = 32; off; off >>= 1) {
            p0 += __shfl_down(p0, off);
            p1 += __shfl_down(p1, off);
        }
        float* red = gs0;  // reuse LDS
        if (lane == 0) { red[r * 2] = p0; red[r * 2 + 1] = p1; }
        __syncthreads();
        if (tid < 2) {
            float s = bd[tid];
            #pragma unroll
            for (int w = 0; w < 8; ++w) s += red[w * 2 + tid];
            out[wg * 2 + tid] = tanhf(s);
        }
    }
}

extern "C" void kernel_launch(void* const* d_in, const int* in_sizes, int n_in,
                              void* d_out, int out_size, void* d_ws, size_t ws_size,
                              hipStream_t stream) {
    const float* x    = (const float*)d_in[0];
    const float* Wih0 = (const float*)d_in[1];
    const float* Whh0 = (const float*)d_in[2];
    const float* bih0 = (const float*)d_in[3];
    const float* bhh0 = (const float*)d_in[4];
    const float* Wih1 = (const float*)d_in[5];
    const float* Whh1 = (const float*)d_in[6];
    const float* bih1 = (const float*)d_in[7];
    const float* bhh1 = (const float*)d_in[8];
    const float* Wd   = (const float*)d_in[9];
    const float* bd   = (const float*)d_in[10];
    float* out = (float*)d_out;
    char* ws = (char*)d_ws;

    hipFuncSetAttribute((const void*)lstm_persist,
                        hipFuncAttributeMaxDynamicSharedMemorySize, LDS_BYTES);

    void* kargs[] = { &x, &Wih0, &Whh0, &bih0, &bhh0, &Wih1, &Whh1, &bih1, &bhh1,
                      &Wd, &bd, &out, &ws };
    hipLaunchCooperativeKernel((void*)lstm_persist, dim3(256), dim3(512),
                               kargs, LDS_BYTES, stream);
}